// Round 17
// baseline (21.558 us; speedup 1.0000x reference)
//
#include <hip/hip_runtime.h>
#include <math.h>

// RKN cell: B=4096, LOD=64, LSD=128, H=64, NB=15, NE=436 (band +-3)
// R17: 512 blocks x 512 thr x 8 rows. LDS 75.7KB -> 2 blocks/CU (two
// independent barrier domains). BAST halved (split-K phase 3, half-B
// restaged); phase-4 state bf16 (R12-validated).
#define O_PM   0
#define O_PCU  524288
#define O_PCL  786432
#define O_PCS  1048576
#define O_NM   1310720
#define O_NCU  1835008
#define O_NCL  2097152
#define O_NCS  2359296

// ---- LDS word map (18928 words = 75712 B -> 2 blocks/CU) ----
// union [0,8384): W1L[64][76] | W2L@4864 [64][44] | W3L@7680 [16][44]
//                 -> tm u16 [8 r][1748] after B4 (6992 words)
// BAST [8384,15376): [4 kp][1748] u32 bf16-pairs (half-K, restaged)
// PMB  [15376,16592): u16 [16 r][152] (rows 8-15 + cols 128-151 zeroed)
// H1 [16592,17296); H2 [17296,18000): u16 [16][88]
// COEF [18000,18160): u16 [16 r][20]
// CUV [18160,18672): u32 [8 r][64] = pk2(pcu,pcl)
// CSV [18672,18928): u16 [8 r][64] = bf16 pcs
#define TM_S   1748
#define L_W1   0
#define L_W2   4864
#define L_W3   7680
#define L_TM   0
#define L_BAST 8384
#define L_PMB  15376
#define L_H1   16592
#define L_H2   17296
#define L_COEF 18000
#define L_CUV  18160
#define L_CSV  18672
#define L_TOT  18928

typedef short s8v __attribute__((ext_vector_type(8)));
typedef short s4v __attribute__((ext_vector_type(4)));
typedef float f4v __attribute__((ext_vector_type(4)));

__device__ __forceinline__ unsigned pk2(float a, float b) {   // 2xf32 -> 2xbf16 RNE
    unsigned ua = __float_as_uint(a), ub = __float_as_uint(b);
    ua += 0x7fffu + ((ua >> 16) & 1u);
    ub += 0x7fffu + ((ub >> 16) & 1u);
    return (ua >> 16) | (ub & 0xffff0000u);
}
__device__ __forceinline__ unsigned short tobf(float a) {
    unsigned ua = __float_as_uint(a);
    ua += 0x7fffu + ((ua >> 16) & 1u);
    return (unsigned short)(ua >> 16);
}
__device__ __forceinline__ float frombf(unsigned short u) {
    return __uint_as_float(((unsigned)u) << 16);
}
__device__ __forceinline__ float lo16(unsigned w) { return __uint_as_float(w << 16); }
__device__ __forceinline__ float hi16(unsigned w) { return __uint_as_float(w & 0xffff0000u); }
__device__ __forceinline__ float frcp(float x) { return __builtin_amdgcn_rcpf(x); }
__device__ __forceinline__ float ftanh(float x) {
    float e = __expf(2.f * x);
    return 1.f - 2.f * frcp(e + 1.f);
}
#define SWZ(v, imm) __uint_as_float((unsigned)__builtin_amdgcn_ds_swizzle((int)__float_as_uint(v), imm))

#if __has_builtin(__builtin_amdgcn_mfma_f32_16x16x16_bf16)
#define MFMA16(A,B,C) __builtin_amdgcn_mfma_f32_16x16x16_bf16(A,B,C,0,0,0)
#elif __has_builtin(__builtin_amdgcn_mfma_f32_16x16x16bf16_1k)
#define MFMA16(A,B,C) __builtin_amdgcn_mfma_f32_16x16x16bf16_1k(A,B,C,0,0,0)
#else
// Host-pass stub only; device pass resolves a real branch (R11-R16 proven).
#define MFMA16(A,B,C) (C)
#endif

__global__ __launch_bounds__(512, 4)
void rkn_kernel(const float* __restrict__ prior_mean,
                const float* __restrict__ cov_u,
                const float* __restrict__ cov_l,
                const float* __restrict__ cov_s,
                const float* __restrict__ obs,
                const float* __restrict__ obs_var,
                const float* __restrict__ W1,
                const float* __restrict__ b1,
                const float* __restrict__ W2,
                const float* __restrict__ b2,
                const float* __restrict__ W3,
                const float* __restrict__ b3,
                const float* __restrict__ tm11b,
                const float* __restrict__ tm12b,
                const float* __restrict__ tm21b,
                const float* __restrict__ tm22b,
                const float* __restrict__ ltn,
                float* __restrict__ out)
{
    __shared__ __align__(16) unsigned smem[L_TOT];

    const int tid  = threadIdx.x;
    const int wid  = tid >> 6;      // 0..7 (wave = row in phases 1/4)
    const int lane = tid & 63;
    const int lrow = lane & 15;     // MFMA operand row / col
    const int lkg  = lane >> 4;     // k-group
    const int row  = blockIdx.x * 8 + wid;

    // ---- stage weights: coalesced float4 reads, bf16-pair LDS writes ----
    {
#pragma unroll
        for (int it = 0; it < 4; ++it) {              // W1: 2048 float4
            const int idx = it * 512 + tid;
            const float4 v = ((const float4*)W1)[idx];
            const int j = idx >> 5, kq = idx & 31;
            unsigned* d = smem + (L_W1 + j * 76 + kq * 2);
            d[0] = pk2(v.x, v.y); d[1] = pk2(v.z, v.w);
        }
#pragma unroll
        for (int it = 0; it < 2; ++it) {              // W2: 1024 float4
            const int idx = it * 512 + tid;
            const float4 v = ((const float4*)W2)[idx];
            const int j = idx >> 4, kq = idx & 15;
            unsigned* d = smem + (L_W2 + j * 44 + kq * 2);
            d[0] = pk2(v.x, v.y); d[1] = pk2(v.z, v.w);
        }
        if (tid < 240) {                              // W3: 15 j x 16 float4
            const float4 v = ((const float4*)W3)[tid];
            const int j = tid >> 4, kq = tid & 15;
            unsigned* d = smem + (L_W3 + j * 44 + kq * 2);
            d[0] = pk2(v.x, v.y); d[1] = pk2(v.z, v.w);
        } else if (tid < 284) {                       // zero W3 row 15
            smem[L_W3 + 15 * 44 + (tid - 240)] = 0u;
        }
    }

    // ---- PMB pad zeroing: rows 8-15 (608 w) + rows 0-7 cols 128-151 (96 w) ----
#pragma unroll
    for (int it = 0; it < 2; ++it) {
        const int idx = it * 512 + tid;
        if (idx < 704) {
            const int w = (idx < 96) ? ((idx / 12) * 76 + 64 + idx % 12)
                                     : (608 + (idx - 96));
            smem[L_PMB + w] = 0u;
        }
    }

    // ---- phase 1: Kalman (wave = row, lane = dim) ----
    {
        const float cu   = cov_u[row * 64 + lane];
        const float cl   = cov_l[row * 64 + lane];
        const float cs   = cov_s[row * 64 + lane];
        const float ob   = obs[row * 64 + lane];
        const float ov   = obs_var[row * 64 + lane];
        const float pmu0 = prior_mean[row * 128 + lane];
        const float pml0 = prior_mean[row * 128 + 64 + lane];

        const float inv = frcp(cu + ov);
        const float qu  = cu * inv;
        const float ql  = cs * inv;
        const float res = ob - pmu0;
        const float pmu = pmu0 + qu * res;
        const float pml = pml0 + ql * res;
        const float cf  = 1.f - qu;
        const float pcu = cf * cu;
        const float pcl = cl - ql * cs;
        const float pcs = cf * cs;

        out[O_PM  + row * 128 + lane]      = pmu;
        out[O_PM  + row * 128 + 64 + lane] = pml;
        out[O_PCU + row * 64 + lane] = pcu;
        out[O_PCL + row * 64 + lane] = pcl;
        out[O_PCS + row * 64 + lane] = pcs;

        unsigned short* pmb16 = (unsigned short*)(smem + L_PMB);
        pmb16[wid * 152 + lane]      = tobf(pmu);
        pmb16[wid * 152 + 64 + lane] = tobf(pml);
        smem[L_CUV + wid * 64 + lane] = pk2(pcu, pcl);
        ((unsigned short*)(smem + L_CSV))[wid * 64 + lane] = tobf(pcs);
    }

    // softplus(trans noise) for phase 4 (per lane)
    const float tcu = __logf(__expf(ltn[lane]) + 1.f);
    const float tcl = __logf(__expf(ltn[64 + lane]) + 1.f);

    __syncthreads();   // B1: weights + pm staged

    // ==== ladder on waves 0-3; BAST half-A staging on waves 4-7 ====
    const int t2 = tid & 255;
    const int ms = t2 & 3;
    const float* bps = (ms == 0) ? tm11b : (ms == 1) ? tm12b : (ms == 2) ? tm21b : tm22b;

    if (wid < 4) {
        const int w = wid;
        f4v acc = {0.f, 0.f, 0.f, 0.f};
#pragma unroll
        for (int s = 0; s < 4; ++s) {                 // layer1: K=128
            s8v a = *(const s8v*)(smem + L_PMB + lrow * 76 + s * 16 + lkg * 4);
            s8v b = *(const s8v*)(smem + L_W1 + (w * 16 + lrow) * 76 + s * 16 + lkg * 4);
            acc = __builtin_amdgcn_mfma_f32_16x16x32_bf16(a, b, acc, 0, 0, 0);
        }
        const float bc1 = b1[w * 16 + lrow];
        unsigned short* h1u = (unsigned short*)(smem + L_H1);
#pragma unroll
        for (int q = 0; q < 4; ++q)
            h1u[(lkg * 4 + q) * 88 + w * 16 + lrow] = tobf(ftanh(acc[q] + bc1));
    } else {
#pragma unroll
        for (int kp = 0; kp < 2; ++kp)                // half-A chunk 1: kp 0,1
#pragma unroll
            for (int c = 0; c < 7; ++c) {
                const int n = c * 256 + t2;
                if (n < 1744) {
                    const int e = n >> 2;
                    smem[L_BAST + kp * TM_S + n] =
                        pk2(bps[(2 * kp) * 436 + e], bps[(2 * kp + 1) * 436 + e]);
                }
            }
    }
    __syncthreads();   // B2: h1 ready

    if (wid < 4) {
        const int w = wid;
        f4v acc = {0.f, 0.f, 0.f, 0.f};
#pragma unroll
        for (int s = 0; s < 2; ++s) {                 // layer2: K=64
            s8v a = *(const s8v*)(smem + L_H1 + lrow * 44 + s * 16 + lkg * 4);
            s8v b = *(const s8v*)(smem + L_W2 + (w * 16 + lrow) * 44 + s * 16 + lkg * 4);
            acc = __builtin_amdgcn_mfma_f32_16x16x32_bf16(a, b, acc, 0, 0, 0);
        }
        const float bc2 = b2[w * 16 + lrow];
        unsigned short* h2u = (unsigned short*)(smem + L_H2);
#pragma unroll
        for (int q = 0; q < 4; ++q)
            h2u[(lkg * 4 + q) * 88 + w * 16 + lrow] = tobf(ftanh(acc[q] + bc2));
    } else {
#pragma unroll
        for (int kp = 2; kp < 4; ++kp)                // half-A chunk 2: kp 2,3
#pragma unroll
            for (int c = 0; c < 7; ++c) {
                const int n = c * 256 + t2;
                if (n < 1744) {
                    const int e = n >> 2;
                    smem[L_BAST + kp * TM_S + n] =
                        pk2(bps[(2 * kp) * 436 + e], bps[(2 * kp + 1) * 436 + e]);
                }
            }
    }
    __syncthreads();   // B3: h2 ready

    if (wid == 0) {
        f4v acc = {0.f, 0.f, 0.f, 0.f};
#pragma unroll
        for (int s = 0; s < 2; ++s) {                 // layer3: K=64, cols 0-14
            s8v a = *(const s8v*)(smem + L_H2 + lrow * 44 + s * 16 + lkg * 4);
            s8v b = *(const s8v*)(smem + L_W3 + lrow * 44 + s * 16 + lkg * 4);
            acc = __builtin_amdgcn_mfma_f32_16x16x32_bf16(a, b, acc, 0, 0, 0);
        }
        const float bc3 = (lrow < 15) ? b3[lrow] : 0.f;
        unsigned short* cfu = (unsigned short*)(smem + L_COEF);
#pragma unroll
        for (int q = 0; q < 4; ++q) {                 // in-frag softmax over cols
            const float lg = acc[q] + bc3;
            float v = (lrow < 15) ? lg : -1e30f;
            v = fmaxf(v, SWZ(v, 0x041F));
            v = fmaxf(v, SWZ(v, 0x081F));
            v = fmaxf(v, SWZ(v, 0x101F));
            v = fmaxf(v, SWZ(v, 0x201F));
            const float ex = (lrow < 15) ? __expf(lg - v) : 0.f;
            float ss = ex;
            ss += SWZ(ss, 0x041F);
            ss += SWZ(ss, 0x081F);
            ss += SWZ(ss, 0x101F);
            ss += SWZ(ss, 0x201F);
            cfu[(lkg * 4 + q) * 20 + lrow] = tobf(ex * frcp(ss));
        }
    }
    __syncthreads();   // B4: coeff + BAST half-A ready

    // ---- phase 3a: d += coeff[k0..7] . basisT[k0..7]  (split-K MFMA) ----
    f4v d[14];
#pragma unroll
    for (int i = 0; i < 14; ++i) d[i] = (f4v){0.f, 0.f, 0.f, 0.f};
    {
        s4v ca = (s4v){0, 0, 0, 0};
        if (lkg < 2) ca = *(const s4v*)(smem + L_COEF + lrow * 10 + lkg * 2);
#pragma unroll
        for (int i = 0; i < 14; ++i) {
            const int t = i * 8 + wid;
            if (t < 109) {
                const int nn = t * 16 + lrow;
                unsigned wp[2] = {0u, 0u};
                if (lkg < 2) {
                    wp[0] = smem[L_BAST + (lkg * 2    ) * TM_S + nn];
                    wp[1] = smem[L_BAST + (lkg * 2 + 1) * TM_S + nn];
                }
                d[i] = MFMA16(ca, *(const s4v*)wp, d[i]);
            }
        }
    }
    __syncthreads();   // B5a: all half-A reads done

    // ---- restage BAST with half-B (k 8..15; k15 -> 0), all 512 threads ----
    {
        const int mb = tid & 3;
        const float* bpb = (mb == 0) ? tm11b : (mb == 1) ? tm12b : (mb == 2) ? tm21b : tm22b;
#pragma unroll
        for (int kp = 0; kp < 4; ++kp)
#pragma unroll
            for (int c = 0; c < 4; ++c) {
                const int n = c * 512 + tid;
                if (n < 1744) {
                    const int e = n >> 2;
                    const float lo = bpb[(8 + 2 * kp) * 436 + e];
                    const float hi = (9 + 2 * kp < 15) ? bpb[(9 + 2 * kp) * 436 + e] : 0.f;
                    smem[L_BAST + kp * TM_S + n] = pk2(lo, hi);
                }
            }
    }
    __syncthreads();   // B5b: half-B staged

    // ---- phase 3b: d += coeff[k8..15] . basisT[k8..15]; write tm rows 0-7 ----
    {
        s4v ca = (s4v){0, 0, 0, 0};
        if (lkg < 2) ca = *(const s4v*)(smem + L_COEF + lrow * 10 + 4 + lkg * 2);
        unsigned short* tmu = (unsigned short*)smem;
#pragma unroll
        for (int i = 0; i < 14; ++i) {
            const int t = i * 8 + wid;
            if (t < 109) {
                const int nn = t * 16 + lrow;
                unsigned wp[2] = {0u, 0u};
                if (lkg < 2) {
                    wp[0] = smem[L_BAST + (lkg * 2    ) * TM_S + nn];
                    wp[1] = smem[L_BAST + (lkg * 2 + 1) * TM_S + nn];
                }
                d[i] = MFMA16(ca, *(const s4v*)wp, d[i]);
                if (lkg < 2) {
#pragma unroll
                    for (int q = 0; q < 4; ++q)
                        tmu[(lkg * 4 + q) * TM_S + nn] = tobf(d[i][q]);
                }
            }
        }
    }
    __syncthreads();   // B5c: tm visible

    // ---- phase 4: banded mat-vec combos; wave = row, bf16 state ----
    {
        const int i   = lane;
        const int jlo = (i - 3 > 0) ? (i - 3) : 0;
        const int ne  = ((i + 3 < 63) ? (i + 3) : 63) - jlo + 1;
        const int base = (i < 4)  ? (i * (i + 7)) / 2
                       : (i <= 61) ? (7 * i - 6)
                       : (i == 62) ? 427 : 432;
        const unsigned short* pmb16 = (const unsigned short*)(smem + L_PMB);
        const unsigned short* csv16 = (const unsigned short*)(smem + L_CSV);
        const uint2* tmr = (const uint2*)smem;   // tm: uint2 idx r*(TM_S/4)+e

        const int r = wid;
        float nmu = 0.f, nml = 0.f, ncu = 0.f, ncl = 0.f, ncs = 0.f;
#pragma unroll
        for (int dd = 0; dd < 7; ++dd) {
            if (dd < ne) {
                const int j = jlo + dd;
                const uint2 tv = tmr[r * (TM_S / 4) + base + dd];
                float t11 = lo16(tv.x);
                float t12 = hi16(tv.x);
                float t21 = lo16(tv.y);
                float t22 = hi16(tv.y);
                if (j == i) { t11 += 1.f; t22 += 1.f; }
                const float mu  = frombf(pmb16[r * 152 + j]);
                const float ml  = frombf(pmb16[r * 152 + 64 + j]);
                const unsigned cc = smem[L_CUV + r * 64 + j];
                const float vcu = lo16(cc);
                const float vcl = hi16(cc);
                const float vcs = frombf(csv16[r * 64 + j]);
                nmu += t11 * mu + t12 * ml;
                nml += t21 * mu + t22 * ml;
                ncu += t11 * t11 * vcu + 2.f * t11 * t12 * vcs + t12 * t12 * vcl;
                ncl += t21 * t21 * vcu + 2.f * t21 * t22 * vcs + t22 * t22 * vcl;
                ncs += t21 * t11 * vcu + (t22 * t11 + t21 * t12) * vcs + t22 * t12 * vcl;
            }
        }
        out[O_NM  + row * 128 + i]      = nmu;
        out[O_NM  + row * 128 + 64 + i] = nml;
        out[O_NCU + row * 64 + i] = ncu + tcu;
        out[O_NCL + row * 64 + i] = ncl + tcl;
        out[O_NCS + row * 64 + i] = ncs;
    }
}

extern "C" void kernel_launch(void* const* d_in, const int* in_sizes, int n_in,
                              void* d_out, int out_size, void* d_ws, size_t ws_size,
                              hipStream_t stream) {
    rkn_kernel<<<dim3(512), dim3(512), 0, stream>>>(
        (const float*)d_in[0],  // prior_mean
        (const float*)d_in[1],  // cov_u
        (const float*)d_in[2],  // cov_l
        (const float*)d_in[3],  // cov_s
        (const float*)d_in[4],  // obs
        (const float*)d_in[5],  // obs_var
        (const float*)d_in[6],  // W1
        (const float*)d_in[7],  // b1
        (const float*)d_in[8],  // W2
        (const float*)d_in[9],  // b2
        (const float*)d_in[10], // W3
        (const float*)d_in[11], // b3
        (const float*)d_in[12], // tm11_basis
        (const float*)d_in[13], // tm12_basis
        (const float*)d_in[14], // tm21_basis
        (const float*)d_in[15], // tm22_basis
        (const float*)d_in[16], // log_trans_noise
        (float*)d_out);
}

// Round 18
// 17.100 us; speedup vs baseline: 1.2607x; 1.2607x over previous
//
#include <hip/hip_runtime.h>
#include <math.h>

// RKN cell: B=4096, LOD=64, LSD=128, H=64, NB=15, NE=436 (band +-3)
// R18: R16 (best, 16.9us) with basis staging REBALANCED: kp0-1 pulled into
// the prologue on otherwise-idle waves 8-15; kp2-3/4-5/6-7 during the three
// ladder intervals (was 3-3-2 on intervals only). Numerics identical to R16.
#define O_PM   0
#define O_PCU  524288
#define O_PCL  786432
#define O_PCS  1048576
#define O_NM   1310720
#define O_NCU  1835008
#define O_NCL  2097152
#define O_NCS  2359296

// ---- LDS word map (35872 words = 143488 B, 1 block/CU) ----
#define TM_S   1748      // tm row stride (u16) / BAST row stride (u32)
#define L_W1   0
#define L_W2   4864
#define L_W3   7680
#define L_TM   0
#define L_BAST 13984
#define L_PMB  27968
#define L_H1   29184
#define L_H2   29888
#define L_COEF 30592
#define L_PMF  30752
#define L_CUF  32800
#define L_CLF  33824
#define L_CSF  34848
#define L_TOT  35872

typedef short s8v __attribute__((ext_vector_type(8)));
typedef short s4v __attribute__((ext_vector_type(4)));
typedef float f4v __attribute__((ext_vector_type(4)));

__device__ __forceinline__ unsigned pk2(float a, float b) {   // 2xf32 -> 2xbf16 RNE
    unsigned ua = __float_as_uint(a), ub = __float_as_uint(b);
    ua += 0x7fffu + ((ua >> 16) & 1u);
    ub += 0x7fffu + ((ub >> 16) & 1u);
    return (ua >> 16) | (ub & 0xffff0000u);
}
__device__ __forceinline__ unsigned short tobf(float a) {
    unsigned ua = __float_as_uint(a);
    ua += 0x7fffu + ((ua >> 16) & 1u);
    return (unsigned short)(ua >> 16);
}
__device__ __forceinline__ float frombf(unsigned short u) {
    return __uint_as_float(((unsigned)u) << 16);
}
__device__ __forceinline__ float lo16(unsigned w) { return __uint_as_float(w << 16); }
__device__ __forceinline__ float hi16(unsigned w) { return __uint_as_float(w & 0xffff0000u); }
__device__ __forceinline__ float frcp(float x) { return __builtin_amdgcn_rcpf(x); }
__device__ __forceinline__ float ftanh(float x) {
    float e = __expf(2.f * x);
    return 1.f - 2.f * frcp(e + 1.f);
}
#define SWZ(v, imm) __uint_as_float((unsigned)__builtin_amdgcn_ds_swizzle((int)__float_as_uint(v), imm))

#if __has_builtin(__builtin_amdgcn_mfma_f32_16x16x16_bf16)
#define MFMA16(A,B,C) __builtin_amdgcn_mfma_f32_16x16x16_bf16(A,B,C,0,0,0)
#elif __has_builtin(__builtin_amdgcn_mfma_f32_16x16x16bf16_1k)
#define MFMA16(A,B,C) __builtin_amdgcn_mfma_f32_16x16x16bf16_1k(A,B,C,0,0,0)
#else
// Host-pass stub only (host clang can't see amdgcn builtins); device pass
// resolves a real branch above (proven by R11-R17 passing).
#define MFMA16(A,B,C) (C)
#endif

__global__ __launch_bounds__(1024, 4)
void rkn_kernel(const float* __restrict__ prior_mean,
                const float* __restrict__ cov_u,
                const float* __restrict__ cov_l,
                const float* __restrict__ cov_s,
                const float* __restrict__ obs,
                const float* __restrict__ obs_var,
                const float* __restrict__ W1,
                const float* __restrict__ b1,
                const float* __restrict__ W2,
                const float* __restrict__ b2,
                const float* __restrict__ W3,
                const float* __restrict__ b3,
                const float* __restrict__ tm11b,
                const float* __restrict__ tm12b,
                const float* __restrict__ tm21b,
                const float* __restrict__ tm22b,
                const float* __restrict__ ltn,
                float* __restrict__ out)
{
    __shared__ __align__(16) unsigned smem[L_TOT];

    const int tid  = threadIdx.x;
    const int wid  = tid >> 6;      // 0..15
    const int lane = tid & 63;
    const int lrow = lane & 15;     // MFMA operand row (A row / B col)
    const int lkg  = lane >> 4;     // k-group

    // ---- stage weights: coalesced float4 reads, bf16-pair LDS writes ----
    {
#pragma unroll
        for (int it = 0; it < 2; ++it) {              // W1: 2048 float4
            const int idx = it * 1024 + tid;
            const float4 v = ((const float4*)W1)[idx];
            const int j = idx >> 5, kq = idx & 31;
            unsigned* d = smem + (L_W1 + j * 76 + kq * 2);
            d[0] = pk2(v.x, v.y); d[1] = pk2(v.z, v.w);
        }
        {                                             // W2: 1024 float4
            const int idx = tid;
            const float4 v = ((const float4*)W2)[idx];
            const int j = idx >> 4, kq = idx & 15;
            unsigned* d = smem + (L_W2 + j * 44 + kq * 2);
            d[0] = pk2(v.x, v.y); d[1] = pk2(v.z, v.w);
        }
        if (tid < 240) {                              // W3: 15 j x 16 float4
            const float4 v = ((const float4*)W3)[tid];
            const int j = tid >> 4, kq = tid & 15;
            unsigned* d = smem + (L_W3 + j * 44 + kq * 2);
            d[0] = pk2(v.x, v.y); d[1] = pk2(v.z, v.w);
        } else if (tid < 284) {                       // zero W3 row 15
            smem[L_W3 + 15 * 44 + (tid - 240)] = 0u;
        }
    }

    // ---- phase 1: Kalman on tid<512 || basisT kp0-1 staging on waves 8-15 ----
    if (tid < 512) {
        const int prow  = tid >> 5;
        const int pd    = (tid & 31) << 1;
        const int grow1 = blockIdx.x * 16 + prow;
        const float2 cu2 = *(const float2*)(cov_u   + grow1 * 64 + pd);
        const float2 cl2 = *(const float2*)(cov_l   + grow1 * 64 + pd);
        const float2 cs2 = *(const float2*)(cov_s   + grow1 * 64 + pd);
        const float2 ob2 = *(const float2*)(obs     + grow1 * 64 + pd);
        const float2 ov2 = *(const float2*)(obs_var + grow1 * 64 + pd);
        const float2 pu2 = *(const float2*)(prior_mean + grow1 * 128 + pd);
        const float2 pl2 = *(const float2*)(prior_mean + grow1 * 128 + 64 + pd);

        const float i0 = frcp(cu2.x + ov2.x), i1 = frcp(cu2.y + ov2.y);
        const float qu0 = cu2.x * i0, qu1 = cu2.y * i1;
        const float ql0 = cs2.x * i0, ql1 = cs2.y * i1;
        const float r0 = ob2.x - pu2.x, r1 = ob2.y - pu2.y;
        const float pmu0 = pu2.x + qu0 * r0, pmu1 = pu2.y + qu1 * r1;
        const float pml0 = pl2.x + ql0 * r0, pml1 = pl2.y + ql1 * r1;
        const float cf0 = 1.f - qu0, cf1 = 1.f - qu1;
        const float pcu0 = cf0 * cu2.x, pcu1 = cf1 * cu2.y;
        const float pcl0 = cl2.x - ql0 * cs2.x, pcl1 = cl2.y - ql1 * cs2.y;
        const float pcs0 = cf0 * cs2.x, pcs1 = cf1 * cs2.y;

        *(float2*)(out + O_PM  + grow1 * 128 + pd)      = make_float2(pmu0, pmu1);
        *(float2*)(out + O_PM  + grow1 * 128 + 64 + pd) = make_float2(pml0, pml1);
        *(float2*)(out + O_PCU + grow1 * 64 + pd) = make_float2(pcu0, pcu1);
        *(float2*)(out + O_PCL + grow1 * 64 + pd) = make_float2(pcl0, pcl1);
        *(float2*)(out + O_PCS + grow1 * 64 + pd) = make_float2(pcs0, pcs1);

        smem[L_PMB + prow * 76 + (pd >> 1)]      = pk2(pmu0, pmu1);
        smem[L_PMB + prow * 76 + 32 + (pd >> 1)] = pk2(pml0, pml1);
        *(float2*)((float*)(smem + L_PMF) + prow * 128 + pd)      = make_float2(pmu0, pmu1);
        *(float2*)((float*)(smem + L_PMF) + prow * 128 + 64 + pd) = make_float2(pml0, pml1);
        *(float2*)((float*)(smem + L_CUF) + prow * 64 + pd) = make_float2(pcu0, pcu1);
        *(float2*)((float*)(smem + L_CLF) + prow * 64 + pd) = make_float2(pcl0, pcl1);
        *(float2*)((float*)(smem + L_CSF) + prow * 64 + pd) = make_float2(pcs0, pcs1);
    } else {
        // waves 8-15 (512 thr): stage basisT kp 0-1 (prologue was idle here)
        const int t3  = tid - 512;                    // 0..511
        const int ms3 = t3 & 3;
        const float* bp3 = (ms3 == 0) ? tm11b : (ms3 == 1) ? tm12b
                         : (ms3 == 2) ? tm21b : tm22b;
#pragma unroll
        for (int kp = 0; kp < 2; ++kp)
#pragma unroll
            for (int c = 0; c < 4; ++c) {
                const int n = c * 512 + t3;
                if (n < 1744) {
                    const int e = n >> 2;
                    smem[L_BAST + kp * TM_S + n] =
                        pk2(bp3[(2 * kp) * 436 + e], bp3[(2 * kp + 1) * 436 + e]);
                }
            }
    }

    // softplus(trans noise) for phase 4 (per lane)
    const float tcu = __logf(__expf(ltn[lane]) + 1.f);
    const float tcl = __logf(__expf(ltn[64 + lane]) + 1.f);

    __syncthreads();   // B1: weights + pm + basisT kp0-1 staged

    // ==== MLP ladder on waves 0-3; basisT kp2-7 on waves 4-15 (2/interval) ====
    const int t2 = tid - 256;                  // valid for wid>=4: 0..767
    const int ms = t2 & 3;
    const float* bps = (ms == 0) ? tm11b : (ms == 1) ? tm12b : (ms == 2) ? tm21b : tm22b;

    if (wid < 4) {
        const int w = wid;
        f4v acc = {0.f, 0.f, 0.f, 0.f};
#pragma unroll
        for (int s = 0; s < 4; ++s) {                 // layer1: K=128
            s8v a = *(const s8v*)(smem + L_PMB + lrow * 76 + s * 16 + lkg * 4);
            s8v b = *(const s8v*)(smem + L_W1 + (w * 16 + lrow) * 76 + s * 16 + lkg * 4);
            acc = __builtin_amdgcn_mfma_f32_16x16x32_bf16(a, b, acc, 0, 0, 0);
        }
        const float bc1 = b1[w * 16 + lrow];
        unsigned short* h1u = (unsigned short*)(smem + L_H1);
#pragma unroll
        for (int q = 0; q < 4; ++q)
            h1u[(lkg * 4 + q) * 88 + w * 16 + lrow] = tobf(ftanh(acc[q] + bc1));
    } else {
#pragma unroll
        for (int kp = 2; kp < 4; ++kp)                // interval 1: kp 2-3
#pragma unroll
            for (int c = 0; c < 3; ++c) {
                const int n = c * 768 + t2;
                if (n < 1744) {
                    const int e = n >> 2;
                    smem[L_BAST + kp * TM_S + n] =
                        pk2(bps[(2 * kp) * 436 + e], bps[(2 * kp + 1) * 436 + e]);
                }
            }
    }
    __syncthreads();   // B2: h1 ready

    if (wid < 4) {
        const int w = wid;
        f4v acc = {0.f, 0.f, 0.f, 0.f};
#pragma unroll
        for (int s = 0; s < 2; ++s) {                 // layer2: K=64
            s8v a = *(const s8v*)(smem + L_H1 + lrow * 44 + s * 16 + lkg * 4);
            s8v b = *(const s8v*)(smem + L_W2 + (w * 16 + lrow) * 44 + s * 16 + lkg * 4);
            acc = __builtin_amdgcn_mfma_f32_16x16x32_bf16(a, b, acc, 0, 0, 0);
        }
        const float bc2 = b2[w * 16 + lrow];
        unsigned short* h2u = (unsigned short*)(smem + L_H2);
#pragma unroll
        for (int q = 0; q < 4; ++q)
            h2u[(lkg * 4 + q) * 88 + w * 16 + lrow] = tobf(ftanh(acc[q] + bc2));
    } else {
#pragma unroll
        for (int kp = 4; kp < 6; ++kp)                // interval 2: kp 4-5
#pragma unroll
            for (int c = 0; c < 3; ++c) {
                const int n = c * 768 + t2;
                if (n < 1744) {
                    const int e = n >> 2;
                    smem[L_BAST + kp * TM_S + n] =
                        pk2(bps[(2 * kp) * 436 + e], bps[(2 * kp + 1) * 436 + e]);
                }
            }
    }
    __syncthreads();   // B3: h2 ready

    if (wid == 0) {
        f4v acc = {0.f, 0.f, 0.f, 0.f};
#pragma unroll
        for (int s = 0; s < 2; ++s) {                 // layer3: K=64, cols 0-14
            s8v a = *(const s8v*)(smem + L_H2 + lrow * 44 + s * 16 + lkg * 4);
            s8v b = *(const s8v*)(smem + L_W3 + lrow * 44 + s * 16 + lkg * 4);
            acc = __builtin_amdgcn_mfma_f32_16x16x32_bf16(a, b, acc, 0, 0, 0);
        }
        const float bc3 = (lrow < 15) ? b3[lrow] : 0.f;
        unsigned short* cfu = (unsigned short*)(smem + L_COEF);
#pragma unroll
        for (int q = 0; q < 4; ++q) {                 // in-frag softmax over cols
            const float lg = acc[q] + bc3;
            float v = (lrow < 15) ? lg : -1e30f;
            v = fmaxf(v, SWZ(v, 0x041F));
            v = fmaxf(v, SWZ(v, 0x081F));
            v = fmaxf(v, SWZ(v, 0x101F));
            v = fmaxf(v, SWZ(v, 0x201F));
            const float ex = (lrow < 15) ? __expf(lg - v) : 0.f;
            float ss = ex;
            ss += SWZ(ss, 0x041F);
            ss += SWZ(ss, 0x081F);
            ss += SWZ(ss, 0x101F);
            ss += SWZ(ss, 0x201F);
            cfu[(lkg * 4 + q) * 20 + lrow] = tobf(ex * frcp(ss));
        }
    } else if (wid >= 4) {
#pragma unroll
        for (int kp = 6; kp < 8; ++kp)                // interval 3: kp 6-7
#pragma unroll
            for (int c = 0; c < 3; ++c) {
                const int n = c * 768 + t2;
                if (n < 1744) {
                    const int e = n >> 2;
                    const float lo = bps[(2 * kp) * 436 + e];
                    const float hi = (kp < 7) ? bps[(2 * kp + 1) * 436 + e] : 0.f;
                    smem[L_BAST + kp * TM_S + n] = pk2(lo, hi);
                }
            }
    }
    __syncthreads();   // B4: coeff + basisT ready; weights dead -> tm region

    // ---- phase 3: tm[16][1744] = coeff[16][15] . basisT (MFMA, 16 waves) ----
    {
        unsigned short* tmu = (unsigned short*)(smem + L_TM);
        const s4v ca = *(const s4v*)(smem + L_COEF + lrow * 10 + lkg * 2);
#pragma unroll
        for (int i = 0; i < 7; ++i) {
            const int t = i * 16 + wid;
            if (t < 109) {
                const int nn = t * 16 + lrow;
                unsigned wpair[2];
                wpair[0] = smem[L_BAST + (lkg * 2    ) * TM_S + nn];
                wpair[1] = smem[L_BAST + (lkg * 2 + 1) * TM_S + nn];
                const s4v bb = *(const s4v*)wpair;
                f4v d = {0.f, 0.f, 0.f, 0.f};
                d = MFMA16(ca, bb, d);
#pragma unroll
                for (int q = 0; q < 4; ++q)
                    tmu[(lkg * 4 + q) * TM_S + nn] = tobf(d[q]);
            }
        }
    }
    __syncthreads();   // B5: tm visible

    // ---- phase 4: banded mat-vec combos; wave = row ----
    {
        const int i   = lane;
        const int jlo = (i - 3 > 0) ? (i - 3) : 0;
        const int ne  = ((i + 3 < 63) ? (i + 3) : 63) - jlo + 1;
        const int base = (i < 4)  ? (i * (i + 7)) / 2
                       : (i <= 61) ? (7 * i - 6)
                       : (i == 62) ? 427 : 432;
        const float* pmf = (const float*)(smem + L_PMF);
        const float* cuf = (const float*)(smem + L_CUF);
        const float* clf = (const float*)(smem + L_CLF);
        const float* csf = (const float*)(smem + L_CSF);
        const uint2* tmr = (const uint2*)smem;   // tm: uint2 idx r*(TM_S/4)+e

        const int r  = wid;
        const int gr = blockIdx.x * 16 + r;
        float nmu = 0.f, nml = 0.f, ncu = 0.f, ncl = 0.f, ncs = 0.f;
#pragma unroll
        for (int dd = 0; dd < 7; ++dd) {
            if (dd < ne) {
                const int j = jlo + dd;
                const uint2 tv = tmr[r * (TM_S / 4) + base + dd];
                float t11 = lo16(tv.x);
                float t12 = hi16(tv.x);
                float t21 = lo16(tv.y);
                float t22 = hi16(tv.y);
                if (j == i) { t11 += 1.f; t22 += 1.f; }
                const float mu  = pmf[r * 128 + j];
                const float ml  = pmf[r * 128 + 64 + j];
                const float vcu = cuf[r * 64 + j];
                const float vcl = clf[r * 64 + j];
                const float vcs = csf[r * 64 + j];
                nmu += t11 * mu + t12 * ml;
                nml += t21 * mu + t22 * ml;
                ncu += t11 * t11 * vcu + 2.f * t11 * t12 * vcs + t12 * t12 * vcl;
                ncl += t21 * t21 * vcu + 2.f * t21 * t22 * vcs + t22 * t22 * vcl;
                ncs += t21 * t11 * vcu + (t22 * t11 + t21 * t12) * vcs + t22 * t12 * vcl;
            }
        }
        out[O_NM  + gr * 128 + i]      = nmu;
        out[O_NM  + gr * 128 + 64 + i] = nml;
        out[O_NCU + gr * 64 + i] = ncu + tcu;
        out[O_NCL + gr * 64 + i] = ncl + tcl;
        out[O_NCS + gr * 64 + i] = ncs;
    }
}

extern "C" void kernel_launch(void* const* d_in, const int* in_sizes, int n_in,
                              void* d_out, int out_size, void* d_ws, size_t ws_size,
                              hipStream_t stream) {
    rkn_kernel<<<dim3(256), dim3(1024), 0, stream>>>(
        (const float*)d_in[0],  // prior_mean
        (const float*)d_in[1],  // cov_u
        (const float*)d_in[2],  // cov_l
        (const float*)d_in[3],  // cov_s
        (const float*)d_in[4],  // obs
        (const float*)d_in[5],  // obs_var
        (const float*)d_in[6],  // W1
        (const float*)d_in[7],  // b1
        (const float*)d_in[8],  // W2
        (const float*)d_in[9],  // b2
        (const float*)d_in[10], // W3
        (const float*)d_in[11], // b3
        (const float*)d_in[12], // tm11_basis
        (const float*)d_in[13], // tm12_basis
        (const float*)d_in[14], // tm21_basis
        (const float*)d_in[15], // tm22_basis
        (const float*)d_in[16], // log_trans_noise
        (float*)d_out);
}

// Round 19
// 16.642 us; speedup vs baseline: 1.2954x; 1.0275x over previous
//
#include <hip/hip_runtime.h>
#include <math.h>

// RKN cell: B=4096, LOD=64, LSD=128, H=64, NB=15, NE=436 (band +-3)
// R19: R16 (best, 16.9us) + s_setprio(1) around the critical-path MLP-wave
// bodies (T5 role-split hint: 1 MFMA wave vs 3 staging waves per SIMD).
#define O_PM   0
#define O_PCU  524288
#define O_PCL  786432
#define O_PCS  1048576
#define O_NM   1310720
#define O_NCU  1835008
#define O_NCL  2097152
#define O_NCS  2359296

// ---- LDS word map (35872 words = 143488 B, 1 block/CU) ----
#define TM_S   1748      // tm row stride (u16) / BAST row stride (u32)
#define L_W1   0
#define L_W2   4864
#define L_W3   7680
#define L_TM   0
#define L_BAST 13984
#define L_PMB  27968
#define L_H1   29184
#define L_H2   29888
#define L_COEF 30592
#define L_PMF  30752
#define L_CUF  32800
#define L_CLF  33824
#define L_CSF  34848
#define L_TOT  35872

typedef short s8v __attribute__((ext_vector_type(8)));
typedef short s4v __attribute__((ext_vector_type(4)));
typedef float f4v __attribute__((ext_vector_type(4)));

__device__ __forceinline__ unsigned pk2(float a, float b) {   // 2xf32 -> 2xbf16 RNE
    unsigned ua = __float_as_uint(a), ub = __float_as_uint(b);
    ua += 0x7fffu + ((ua >> 16) & 1u);
    ub += 0x7fffu + ((ub >> 16) & 1u);
    return (ua >> 16) | (ub & 0xffff0000u);
}
__device__ __forceinline__ unsigned short tobf(float a) {
    unsigned ua = __float_as_uint(a);
    ua += 0x7fffu + ((ua >> 16) & 1u);
    return (unsigned short)(ua >> 16);
}
__device__ __forceinline__ float frombf(unsigned short u) {
    return __uint_as_float(((unsigned)u) << 16);
}
__device__ __forceinline__ float lo16(unsigned w) { return __uint_as_float(w << 16); }
__device__ __forceinline__ float hi16(unsigned w) { return __uint_as_float(w & 0xffff0000u); }
__device__ __forceinline__ float frcp(float x) { return __builtin_amdgcn_rcpf(x); }
__device__ __forceinline__ float ftanh(float x) {
    float e = __expf(2.f * x);
    return 1.f - 2.f * frcp(e + 1.f);
}
#define SWZ(v, imm) __uint_as_float((unsigned)__builtin_amdgcn_ds_swizzle((int)__float_as_uint(v), imm))

#if __has_builtin(__builtin_amdgcn_mfma_f32_16x16x16_bf16)
#define MFMA16(A,B,C) __builtin_amdgcn_mfma_f32_16x16x16_bf16(A,B,C,0,0,0)
#elif __has_builtin(__builtin_amdgcn_mfma_f32_16x16x16bf16_1k)
#define MFMA16(A,B,C) __builtin_amdgcn_mfma_f32_16x16x16bf16_1k(A,B,C,0,0,0)
#else
// Host-pass stub only (host clang can't see amdgcn builtins); device pass
// resolves a real branch above (proven by R11-R18 passing).
#define MFMA16(A,B,C) (C)
#endif

#if __has_builtin(__builtin_amdgcn_s_setprio)
#define SETPRIO(n) __builtin_amdgcn_s_setprio(n)
#else
#define SETPRIO(n)
#endif

__global__ __launch_bounds__(1024, 4)
void rkn_kernel(const float* __restrict__ prior_mean,
                const float* __restrict__ cov_u,
                const float* __restrict__ cov_l,
                const float* __restrict__ cov_s,
                const float* __restrict__ obs,
                const float* __restrict__ obs_var,
                const float* __restrict__ W1,
                const float* __restrict__ b1,
                const float* __restrict__ W2,
                const float* __restrict__ b2,
                const float* __restrict__ W3,
                const float* __restrict__ b3,
                const float* __restrict__ tm11b,
                const float* __restrict__ tm12b,
                const float* __restrict__ tm21b,
                const float* __restrict__ tm22b,
                const float* __restrict__ ltn,
                float* __restrict__ out)
{
    __shared__ __align__(16) unsigned smem[L_TOT];

    const int tid  = threadIdx.x;
    const int wid  = tid >> 6;      // 0..15
    const int lane = tid & 63;
    const int lrow = lane & 15;     // MFMA operand row (A row / B col)
    const int lkg  = lane >> 4;     // k-group

    // ---- stage weights: coalesced float4 reads, bf16-pair LDS writes ----
    {
#pragma unroll
        for (int it = 0; it < 2; ++it) {              // W1: 2048 float4
            const int idx = it * 1024 + tid;
            const float4 v = ((const float4*)W1)[idx];
            const int j = idx >> 5, kq = idx & 31;
            unsigned* d = smem + (L_W1 + j * 76 + kq * 2);
            d[0] = pk2(v.x, v.y); d[1] = pk2(v.z, v.w);
        }
        {                                             // W2: 1024 float4
            const int idx = tid;
            const float4 v = ((const float4*)W2)[idx];
            const int j = idx >> 4, kq = idx & 15;
            unsigned* d = smem + (L_W2 + j * 44 + kq * 2);
            d[0] = pk2(v.x, v.y); d[1] = pk2(v.z, v.w);
        }
        if (tid < 240) {                              // W3: 15 j x 16 float4
            const float4 v = ((const float4*)W3)[tid];
            const int j = tid >> 4, kq = tid & 15;
            unsigned* d = smem + (L_W3 + j * 44 + kq * 2);
            d[0] = pk2(v.x, v.y); d[1] = pk2(v.z, v.w);
        } else if (tid < 284) {                       // zero W3 row 15
            smem[L_W3 + 15 * 44 + (tid - 240)] = 0u;
        }
    }

    // ---- phase 1: Kalman on tid<512 (row = tid>>5, dims pd,pd+1) ----
    if (tid < 512) {
        const int prow  = tid >> 5;
        const int pd    = (tid & 31) << 1;
        const int grow1 = blockIdx.x * 16 + prow;
        const float2 cu2 = *(const float2*)(cov_u   + grow1 * 64 + pd);
        const float2 cl2 = *(const float2*)(cov_l   + grow1 * 64 + pd);
        const float2 cs2 = *(const float2*)(cov_s   + grow1 * 64 + pd);
        const float2 ob2 = *(const float2*)(obs     + grow1 * 64 + pd);
        const float2 ov2 = *(const float2*)(obs_var + grow1 * 64 + pd);
        const float2 pu2 = *(const float2*)(prior_mean + grow1 * 128 + pd);
        const float2 pl2 = *(const float2*)(prior_mean + grow1 * 128 + 64 + pd);

        const float i0 = frcp(cu2.x + ov2.x), i1 = frcp(cu2.y + ov2.y);
        const float qu0 = cu2.x * i0, qu1 = cu2.y * i1;
        const float ql0 = cs2.x * i0, ql1 = cs2.y * i1;
        const float r0 = ob2.x - pu2.x, r1 = ob2.y - pu2.y;
        const float pmu0 = pu2.x + qu0 * r0, pmu1 = pu2.y + qu1 * r1;
        const float pml0 = pl2.x + ql0 * r0, pml1 = pl2.y + ql1 * r1;
        const float cf0 = 1.f - qu0, cf1 = 1.f - qu1;
        const float pcu0 = cf0 * cu2.x, pcu1 = cf1 * cu2.y;
        const float pcl0 = cl2.x - ql0 * cs2.x, pcl1 = cl2.y - ql1 * cs2.y;
        const float pcs0 = cf0 * cs2.x, pcs1 = cf1 * cs2.y;

        *(float2*)(out + O_PM  + grow1 * 128 + pd)      = make_float2(pmu0, pmu1);
        *(float2*)(out + O_PM  + grow1 * 128 + 64 + pd) = make_float2(pml0, pml1);
        *(float2*)(out + O_PCU + grow1 * 64 + pd) = make_float2(pcu0, pcu1);
        *(float2*)(out + O_PCL + grow1 * 64 + pd) = make_float2(pcl0, pcl1);
        *(float2*)(out + O_PCS + grow1 * 64 + pd) = make_float2(pcs0, pcs1);

        smem[L_PMB + prow * 76 + (pd >> 1)]      = pk2(pmu0, pmu1);
        smem[L_PMB + prow * 76 + 32 + (pd >> 1)] = pk2(pml0, pml1);
        *(float2*)((float*)(smem + L_PMF) + prow * 128 + pd)      = make_float2(pmu0, pmu1);
        *(float2*)((float*)(smem + L_PMF) + prow * 128 + 64 + pd) = make_float2(pml0, pml1);
        *(float2*)((float*)(smem + L_CUF) + prow * 64 + pd) = make_float2(pcu0, pcu1);
        *(float2*)((float*)(smem + L_CLF) + prow * 64 + pd) = make_float2(pcl0, pcl1);
        *(float2*)((float*)(smem + L_CSF) + prow * 64 + pd) = make_float2(pcs0, pcs1);
    }

    // softplus(trans noise) for phase 4 (per lane)
    const float tcu = __logf(__expf(ltn[lane]) + 1.f);
    const float tcl = __logf(__expf(ltn[64 + lane]) + 1.f);

    __syncthreads();   // B1: weights + pm staged (basisT NOT needed yet)

    // ==== MLP ladder on waves 0-3; basisT staging on waves 4-15 (overlap) ====
    const int t2 = tid - 256;                  // valid for wid>=4: 0..767
    const int ms = t2 & 3;
    const float* bps = (ms == 0) ? tm11b : (ms == 1) ? tm12b : (ms == 2) ? tm21b : tm22b;

    if (wid < 4) {
        SETPRIO(1);
        const int w = wid;
        f4v acc = {0.f, 0.f, 0.f, 0.f};
#pragma unroll
        for (int s = 0; s < 4; ++s) {                 // layer1: K=128
            s8v a = *(const s8v*)(smem + L_PMB + lrow * 76 + s * 16 + lkg * 4);
            s8v b = *(const s8v*)(smem + L_W1 + (w * 16 + lrow) * 76 + s * 16 + lkg * 4);
            acc = __builtin_amdgcn_mfma_f32_16x16x32_bf16(a, b, acc, 0, 0, 0);
        }
        const float bc1 = b1[w * 16 + lrow];
        unsigned short* h1u = (unsigned short*)(smem + L_H1);
#pragma unroll
        for (int q = 0; q < 4; ++q)
            h1u[(lkg * 4 + q) * 88 + w * 16 + lrow] = tobf(ftanh(acc[q] + bc1));
        SETPRIO(0);
    } else {
#pragma unroll
        for (int kp = 0; kp < 3; ++kp)                // chunk 1: kp 0-2
#pragma unroll
            for (int c = 0; c < 3; ++c) {
                const int n = c * 768 + t2;
                if (n < 1744) {
                    const int e = n >> 2;
                    const float lo = bps[(2 * kp) * 436 + e];
                    const float hi = bps[(2 * kp + 1) * 436 + e];
                    smem[L_BAST + kp * TM_S + n] = pk2(lo, hi);
                }
            }
    }
    __syncthreads();   // B2: h1 ready

    if (wid < 4) {
        SETPRIO(1);
        const int w = wid;
        f4v acc = {0.f, 0.f, 0.f, 0.f};
#pragma unroll
        for (int s = 0; s < 2; ++s) {                 // layer2: K=64
            s8v a = *(const s8v*)(smem + L_H1 + lrow * 44 + s * 16 + lkg * 4);
            s8v b = *(const s8v*)(smem + L_W2 + (w * 16 + lrow) * 44 + s * 16 + lkg * 4);
            acc = __builtin_amdgcn_mfma_f32_16x16x32_bf16(a, b, acc, 0, 0, 0);
        }
        const float bc2 = b2[w * 16 + lrow];
        unsigned short* h2u = (unsigned short*)(smem + L_H2);
#pragma unroll
        for (int q = 0; q < 4; ++q)
            h2u[(lkg * 4 + q) * 88 + w * 16 + lrow] = tobf(ftanh(acc[q] + bc2));
        SETPRIO(0);
    } else {
#pragma unroll
        for (int kp = 3; kp < 6; ++kp)                // chunk 2: kp 3-5
#pragma unroll
            for (int c = 0; c < 3; ++c) {
                const int n = c * 768 + t2;
                if (n < 1744) {
                    const int e = n >> 2;
                    const float lo = bps[(2 * kp) * 436 + e];
                    const float hi = bps[(2 * kp + 1) * 436 + e];
                    smem[L_BAST + kp * TM_S + n] = pk2(lo, hi);
                }
            }
    }
    __syncthreads();   // B3: h2 ready

    if (wid == 0) {
        SETPRIO(1);
        f4v acc = {0.f, 0.f, 0.f, 0.f};
#pragma unroll
        for (int s = 0; s < 2; ++s) {                 // layer3: K=64, cols 0-14
            s8v a = *(const s8v*)(smem + L_H2 + lrow * 44 + s * 16 + lkg * 4);
            s8v b = *(const s8v*)(smem + L_W3 + lrow * 44 + s * 16 + lkg * 4);
            acc = __builtin_amdgcn_mfma_f32_16x16x32_bf16(a, b, acc, 0, 0, 0);
        }
        const float bc3 = (lrow < 15) ? b3[lrow] : 0.f;
        unsigned short* cfu = (unsigned short*)(smem + L_COEF);
#pragma unroll
        for (int q = 0; q < 4; ++q) {                 // in-frag softmax over cols
            const float lg = acc[q] + bc3;
            float v = (lrow < 15) ? lg : -1e30f;
            v = fmaxf(v, SWZ(v, 0x041F));
            v = fmaxf(v, SWZ(v, 0x081F));
            v = fmaxf(v, SWZ(v, 0x101F));
            v = fmaxf(v, SWZ(v, 0x201F));
            const float ex = (lrow < 15) ? __expf(lg - v) : 0.f;
            float ss = ex;
            ss += SWZ(ss, 0x041F);
            ss += SWZ(ss, 0x081F);
            ss += SWZ(ss, 0x101F);
            ss += SWZ(ss, 0x201F);
            cfu[(lkg * 4 + q) * 20 + lrow] = tobf(ex * frcp(ss));
        }
        SETPRIO(0);
    } else if (wid >= 4) {
#pragma unroll
        for (int kp = 6; kp < 8; ++kp)                // chunk 3: kp 6-7
#pragma unroll
            for (int c = 0; c < 3; ++c) {
                const int n = c * 768 + t2;
                if (n < 1744) {
                    const int e = n >> 2;
                    const float lo = bps[(2 * kp) * 436 + e];
                    const float hi = (kp < 7) ? bps[(2 * kp + 1) * 436 + e] : 0.f;
                    smem[L_BAST + kp * TM_S + n] = pk2(lo, hi);
                }
            }
    }
    __syncthreads();   // B4: coeff + basisT ready; weights dead -> tm region

    // ---- phase 3: tm[16][1744] = coeff[16][15] . basisT (MFMA, 16 waves) ----
    {
        unsigned short* tmu = (unsigned short*)(smem + L_TM);
        const s4v ca = *(const s4v*)(smem + L_COEF + lrow * 10 + lkg * 2);
#pragma unroll
        for (int i = 0; i < 7; ++i) {
            const int t = i * 16 + wid;
            if (t < 109) {
                const int nn = t * 16 + lrow;
                unsigned wpair[2];
                wpair[0] = smem[L_BAST + (lkg * 2    ) * TM_S + nn];
                wpair[1] = smem[L_BAST + (lkg * 2 + 1) * TM_S + nn];
                const s4v bb = *(const s4v*)wpair;
                f4v d = {0.f, 0.f, 0.f, 0.f};
                d = MFMA16(ca, bb, d);
#pragma unroll
                for (int q = 0; q < 4; ++q)
                    tmu[(lkg * 4 + q) * TM_S + nn] = tobf(d[q]);
            }
        }
    }
    __syncthreads();   // B5: tm visible

    // ---- phase 4: banded mat-vec combos; wave = row ----
    {
        const int i   = lane;
        const int jlo = (i - 3 > 0) ? (i - 3) : 0;
        const int ne  = ((i + 3 < 63) ? (i + 3) : 63) - jlo + 1;
        const int base = (i < 4)  ? (i * (i + 7)) / 2
                       : (i <= 61) ? (7 * i - 6)
                       : (i == 62) ? 427 : 432;
        const float* pmf = (const float*)(smem + L_PMF);
        const float* cuf = (const float*)(smem + L_CUF);
        const float* clf = (const float*)(smem + L_CLF);
        const float* csf = (const float*)(smem + L_CSF);
        const uint2* tmr = (const uint2*)smem;   // tm: uint2 idx r*(TM_S/4)+e

        const int r  = wid;
        const int gr = blockIdx.x * 16 + r;
        float nmu = 0.f, nml = 0.f, ncu = 0.f, ncl = 0.f, ncs = 0.f;
#pragma unroll
        for (int dd = 0; dd < 7; ++dd) {
            if (dd < ne) {
                const int j = jlo + dd;
                const uint2 tv = tmr[r * (TM_S / 4) + base + dd];
                float t11 = lo16(tv.x);
                float t12 = hi16(tv.x);
                float t21 = lo16(tv.y);
                float t22 = hi16(tv.y);
                if (j == i) { t11 += 1.f; t22 += 1.f; }
                const float mu  = pmf[r * 128 + j];
                const float ml  = pmf[r * 128 + 64 + j];
                const float vcu = cuf[r * 64 + j];
                const float vcl = clf[r * 64 + j];
                const float vcs = csf[r * 64 + j];
                nmu += t11 * mu + t12 * ml;
                nml += t21 * mu + t22 * ml;
                ncu += t11 * t11 * vcu + 2.f * t11 * t12 * vcs + t12 * t12 * vcl;
                ncl += t21 * t21 * vcu + 2.f * t21 * t22 * vcs + t22 * t22 * vcl;
                ncs += t21 * t11 * vcu + (t22 * t11 + t21 * t12) * vcs + t22 * t12 * vcl;
            }
        }
        out[O_NM  + gr * 128 + i]      = nmu;
        out[O_NM  + gr * 128 + 64 + i] = nml;
        out[O_NCU + gr * 64 + i] = ncu + tcu;
        out[O_NCL + gr * 64 + i] = ncl + tcl;
        out[O_NCS + gr * 64 + i] = ncs;
    }
}

extern "C" void kernel_launch(void* const* d_in, const int* in_sizes, int n_in,
                              void* d_out, int out_size, void* d_ws, size_t ws_size,
                              hipStream_t stream) {
    rkn_kernel<<<dim3(256), dim3(1024), 0, stream>>>(
        (const float*)d_in[0],  // prior_mean
        (const float*)d_in[1],  // cov_u
        (const float*)d_in[2],  // cov_l
        (const float*)d_in[3],  // cov_s
        (const float*)d_in[4],  // obs
        (const float*)d_in[5],  // obs_var
        (const float*)d_in[6],  // W1
        (const float*)d_in[7],  // b1
        (const float*)d_in[8],  // W2
        (const float*)d_in[9],  // b2
        (const float*)d_in[10], // W3
        (const float*)d_in[11], // b3
        (const float*)d_in[12], // tm11_basis
        (const float*)d_in[13], // tm12_basis
        (const float*)d_in[14], // tm21_basis
        (const float*)d_in[15], // tm22_basis
        (const float*)d_in[16], // log_trans_noise
        (float*)d_out);
}